// Round 1
// baseline (108.616 us; speedup 1.0000x reference)
//
#include <hip/hip_runtime.h>
#include <math.h>

#define H 256
#define OUTD 218
#define OUTP 224
#define BMT 64                  // rows per tile
#define NBATCH 64
#define NPTS 4096
#define NTOT (NBATCH * NPTS)
#define NBLK 256                // persistent blocks, 1 per CU
#define TPB 16                  // tiles per block = NTOT/BMT/NBLK
#define THREADS 512
#define PCOLS 218               // 217 numerator cols + denom

typedef __attribute__((ext_vector_type(8))) short bf16x8;
typedef __attribute__((ext_vector_type(4))) float f32x4;

// hardware RNE f32->bf16 (single)
static __device__ __forceinline__ unsigned short f2bf1(float f) {
  unsigned int t;
  asm("v_cvt_pk_bf16_f32 %0, %1, %1" : "=v"(t) : "v"(f));
  return (unsigned short)t;
}
// hardware RNE f32x2 -> packed bf16x2
static __device__ __forceinline__ unsigned int cvtpk(float lo, float hi) {
  unsigned int t;
  asm("v_cvt_pk_bf16_f32 %0, %1, %2" : "=v"(t) : "v"(lo), "v"(hi));
  return t;
}
static __device__ __forceinline__ bf16x8 pack8(float4 a, float4 b) {
  union { unsigned int u[4]; bf16x8 v; } r;
  r.u[0] = cvtpk(a.x, a.y);
  r.u[1] = cvtpk(a.z, a.w);
  r.u[2] = cvtpk(b.x, b.y);
  r.u[3] = cvtpk(b.z, b.w);
  return r.v;
}

// W1T[j][k] = bf16(W1[k][j]) (256x256); W2T[j][k] = bf16(W2[k][j]) (224x256, padded)
__global__ __launch_bounds__(256) void prep_kernel(
    const float* __restrict__ W1, const float* __restrict__ W2,
    unsigned short* __restrict__ w1t, unsigned short* __restrict__ w2t) {
  int j = blockIdx.x;
  int k = threadIdx.x;
  if (j < H) {
    w1t[j * H + k] = f2bf1(W1[k * H + j]);
  } else {
    int jj = j - H;
    w2t[jj * H + k] = (jj < OUTD) ? f2bf1(W2[k * OUTD + jj]) : (unsigned short)0;
  }
}

// raw barrier that drains LDS ops only (keeps global loads in flight)
#define BAR()                                            \
  {                                                      \
    asm volatile("s_waitcnt lgkmcnt(0)" ::: "memory");   \
    __builtin_amdgcn_s_barrier();                        \
  }

__global__ __launch_bounds__(THREADS, 2) void fused_kernel(
    const float* __restrict__ pe, const float* __restrict__ b1g,
    const float* __restrict__ b2g, const unsigned short* __restrict__ w1t,
    const unsigned short* __restrict__ w2t, float* __restrict__ part) {
  // no f32 stage buffer anymore: pe is reg-staged and converted directly
  __shared__ __align__(16) unsigned short afrag[2 * BMT * H];  // 2 x 32 KB fragment-linear bf16
  __shared__ __align__(16) float e_lds[BMT];

  const int tid = threadIdx.x;
  const int blk = blockIdx.x;
  const int w = tid >> 6;
  const int l = tid & 63;
  const int l15 = l & 15;
  const int hi = l >> 4;
  const size_t row0 = (size_t)blk * (BMT * TPB);   // 1024 rows/block, batch = blk>>2

  // ---- persistent B fragments (loaded once; steady state VMEM = pe prefetch only) ----
  const int nct2 = (w < 6) ? 2 : 1;
  bf16x8 b1r[2][8], b2r[2][8];
  int jcol[2];
  float bc1[2], bj2[2];
  #pragma unroll
  for (int cc = 0; cc < 2; ++cc) {
    const int col1 = (2 * w + cc) * 16 + l15;
    const int ct2 = (w < 6) ? (2 * w + cc) : (6 + w);  // w6->12, w7->13
    const int col2 = ct2 * 16 + l15;
    jcol[cc] = col2;
    bc1[cc] = b1g[col1];
    bj2[cc] = (col2 < OUTD) ? b2g[col2] : 0.f;
    #pragma unroll
    for (int s = 0; s < 8; ++s) {
      const int k0 = s * 32 + hi * 8;
      b1r[cc][s] = *reinterpret_cast<const bf16x8*>(w1t + col1 * H + k0);
      b2r[cc][s] = *reinterpret_cast<const bf16x8*>(w2t + col2 * H + k0);
    }
  }
  const float b2c0 = b2g[0];

  // ---- reg-staged prefetch: tile T's pe rows -> ld[4][2] (32 VGPRs in flight) ----
  // unit idx = tid + j2*512: row = idx>>5, k8 = idx&31 -> lane's 32B at pe[row][k8*8..+7]
  // wave covers 2 contiguous rows (2 KB) per j2 -> fully coalesced
  float4 ld[4][2];
#define ISSUE(T)                                                             \
  {                                                                          \
    const float* g = pe + (row0 + (size_t)(T) * BMT) * H;                    \
    _Pragma("unroll") for (int j2 = 0; j2 < 4; ++j2) {                       \
      const int idx = tid + j2 * THREADS;                                    \
      const float* a = g + (idx >> 5) * H + (idx & 31) * 8;                  \
      ld[j2][0] = *(const float4*)a;                                         \
      ld[j2][1] = *(const float4*)(a + 4);                                   \
    }                                                                        \
  }

  // ---- convert one unit: regs f32 -> afrag[buf] bf16, fragment-linear layout ----
  // element (row,k): f=row>>4, s=k8>>2; p = (ll*4 + hh + s) & 63  (bank-uniform
  // write, matches GEMM read p = (l15*4 + hi + s) & 63 exactly — layout unchanged)
#define CVTU(buf, j2u)                                                       \
  {                                                                          \
    unsigned short* dst = afrag + (buf) * (BMT * H);                         \
    const int idx = tid + (j2u) * THREADS;                                   \
    const int row = idx >> 5, k8 = idx & 31;                                 \
    const int ff = row >> 4, ss = k8 >> 2, hh = k8 & 3, ll = row & 15;       \
    const int p = (ll * 4 + hh + ss) & 63;                                   \
    *(bf16x8*)&dst[(ff * 8 + ss) * 512 + p * 8] = pack8(ld[j2u][0], ld[j2u][1]); \
  }

  // ---- prologue: stage tile 0, then put tile 1 in flight ----
  ISSUE(0);
  __builtin_amdgcn_sched_barrier(0);
  CVTU(0, 0); CVTU(0, 1); CVTU(0, 2); CVTU(0, 3);
  BAR();
  ISSUE(1);

  float psum[2] = {0.f, 0.f};
  float dsum = 0.f;
  int cur = 0;

  for (int t = 0; t < TPB; ++t) {
    const unsigned short* A = afrag + cur * (BMT * H);
    unsigned short* Aw = afrag + cur * (BMT * H);
    const int nb = cur ^ 1;
    const bool doCvt = (t + 1 < TPB);

    // ---- GEMM1: 4 f-frags x 2 coltiles, k=256 ----
    f32x4 acc[4][2];
    #pragma unroll
    for (int f = 0; f < 4; ++f) { acc[f][0] = (f32x4)0.f; acc[f][1] = (f32x4)0.f; }
    #pragma unroll
    for (int s = 0; s < 8; ++s) {
      const int p = (l15 * 4 + hi + s) & 63;
      bf16x8 af[4];
      #pragma unroll
      for (int f = 0; f < 4; ++f)
        af[f] = *(const bf16x8*)&A[(f * 8 + s) * 512 + p * 8];
      #pragma unroll
      for (int f = 0; f < 4; ++f) {
        acc[f][0] = __builtin_amdgcn_mfma_f32_16x16x32_bf16(af[f], b1r[0][s], acc[f][0], 0, 0, 0);
        acc[f][1] = __builtin_amdgcn_mfma_f32_16x16x32_bf16(af[f], b1r[1][s], acc[f][1], 0, 0, 0);
      }
    }
    BAR();  // all A reads done before h overwrites

    // ---- h = leaky(acc + b1) -> fragment-linear layout in same buffer ----
    #pragma unroll
    for (int cc = 0; cc < 2; ++cc) {
      const int col_c0 = (2 * w + cc) * 16 + l15;     // GEMM1 output col
      const int s2 = col_c0 >> 5;
      const int hb = (col_c0 >> 3) & 3;
      const int j2 = col_c0 & 7;
      #pragma unroll
      for (int f = 0; f < 4; ++f) {
        #pragma unroll
        for (int r = 0; r < 4; ++r) {
          const int rl = hi * 4 + r;                  // row_c & 15
          float hv = acc[f][cc][r] + bc1[cc];
          hv = fmaxf(hv, 0.02f * hv);                 // leaky relu, 2 ops
          const int p2 = (rl * 4 + hb + s2) & 63;
          Aw[(f * 8 + s2) * 512 + p2 * 8 + j2] = f2bf1(hv);
        }
      }
    }
    BAR();  // h visible

    // ---- GEMM2: ae = h @ W2, with next-tile convert hidden under the MFMAs ----
    // afrag[nb] is provably free here (its last readers finished before the
    // e-barrier of tile t-1); CVT's ds_writes drain at the e-barrier below.
    #pragma unroll
    for (int f = 0; f < 4; ++f) { acc[f][0] = (f32x4)0.f; acc[f][1] = (f32x4)0.f; }
    #pragma unroll
    for (int s = 0; s < 8; ++s) {
      const int p = (l15 * 4 + hi + s) & 63;
      bf16x8 af[4];
      #pragma unroll
      for (int f = 0; f < 4; ++f)
        af[f] = *(const bf16x8*)&A[(f * 8 + s) * 512 + p * 8];
      #pragma unroll
      for (int f = 0; f < 4; ++f) {
        acc[f][0] = __builtin_amdgcn_mfma_f32_16x16x32_bf16(af[f], b2r[0][s], acc[f][0], 0, 0, 0);
      }
      if (nct2 == 2) {
        #pragma unroll
        for (int f = 0; f < 4; ++f) {
          acc[f][1] = __builtin_amdgcn_mfma_f32_16x16x32_bf16(af[f], b2r[1][s], acc[f][1], 0, 0, 0);
        }
      }
      if (doCvt && (s & 1)) {
        CVTU(nb, (s >> 1));   // VALU+ds_write overlaps the MFMA stream
      }
    }
    if (t + 2 < TPB) ISSUE(t + 2);   // regs free again; max flight time

    // ---- e = exp(logit): col 0 lives in wave 0, lanes l15==0 ----
    if (w == 0 && l15 == 0) {
      #pragma unroll
      for (int f = 0; f < 4; ++f) {
        #pragma unroll
        for (int r = 0; r < 4; ++r) {
          e_lds[f * 16 + hi * 4 + r] = __expf(acc[f][0][r] + b2c0);
        }
      }
    }
    BAR();  // e_lds visible; A reads done; CVT writes to afrag[nb] drained

    // ---- accumulate softmax-weighted partials in registers ----
    #pragma unroll
    for (int f = 0; f < 4; ++f) {
      const f32x4 ev = *(const f32x4*)&e_lds[f * 16 + hi * 4];
      #pragma unroll
      for (int r = 0; r < 4; ++r) {
        psum[0] += ev[r] * (acc[f][0][r] + bj2[0]);
        if (nct2 == 2) psum[1] += ev[r] * (acc[f][1][r] + bj2[1]);
      }
    }
    if (w == 1) dsum += e_lds[l];

    cur ^= 1;
  }

  // ---- store per-block partials (no atomics) ----
  #pragma unroll
  for (int cc = 0; cc < 2; ++cc) {
    psum[cc] += __shfl_xor(psum[cc], 16);
    psum[cc] += __shfl_xor(psum[cc], 32);
  }
  if (hi == 0) {
    for (int cc = 0; cc < nct2; ++cc) {
      int j = jcol[cc];
      if (j >= 1 && j < OUTD) part[blk * PCOLS + (j - 1)] = psum[cc];
    }
  }
  if (w == 1) {
    #pragma unroll
    for (int m = 1; m < 64; m <<= 1) dsum += __shfl_xor(dsum, m);
    if (l == 0) part[blk * PCOLS + 217] = dsum;
  }
#undef ISSUE
#undef CVTU
}

__global__ __launch_bounds__(256) void finalize_kernel(
    const float* __restrict__ part, float* __restrict__ out) {
  int b = blockIdx.x;
  int t = threadIdx.x;
  if (t < 217) {
    float s = 0.f, d = 0.f;
    #pragma unroll
    for (int i = 0; i < NBLK / NBATCH; ++i) {   // 4 blocks per batch
      const float* p = part + (size_t)(b * (NBLK / NBATCH) + i) * PCOLS;
      s += p[t];
      d += p[217];
    }
    float v = s / d;
    if (t < 216) out[b * 216 + t] = v;        // xr: (64, 72, 3) flat
    else out[NBATCH * 216 + b] = v;           // xo: (64,)
  }
}

extern "C" void kernel_launch(void* const* d_in, const int* in_sizes, int n_in,
                              void* d_out, int out_size, void* d_ws, size_t ws_size,
                              hipStream_t stream) {
  (void)in_sizes; (void)n_in; (void)out_size; (void)ws_size;
  const float* pe = (const float*)d_in[0];
  const float* W1 = (const float*)d_in[1];
  const float* b1 = (const float*)d_in[2];
  const float* W2 = (const float*)d_in[3];
  const float* b2 = (const float*)d_in[4];

  unsigned short* w1t = (unsigned short*)d_ws;          // 131072 B
  unsigned short* w2t = w1t + H * H;                    // 114688 B
  float* part = (float*)((char*)d_ws + (H * H + OUTP * H) * 2);  // 256*218*4 B

  prep_kernel<<<H + OUTP, 256, 0, stream>>>(W1, W2, w1t, w2t);
  fused_kernel<<<NBLK, THREADS, 0, stream>>>(pe, b1, b2, w1t, w2t, part);
  finalize_kernel<<<NBATCH, 256, 0, stream>>>(part, (float*)d_out);
}

// Round 2
// 95.866 us; speedup vs baseline: 1.1330x; 1.1330x over previous
//
#include <hip/hip_runtime.h>
#include <math.h>

#define H 256
#define OUTD 218
#define OUTP 224
#define BMT 64                  // rows per tile
#define NBATCH 64
#define NPTS 4096
#define NTOT (NBATCH * NPTS)
#define NBLK 256                // persistent blocks, 1 per CU
#define TPB 16                  // tiles per block = NTOT/BMT/NBLK
#define THREADS 512
#define PCOLS 218               // 217 numerator cols + denom

typedef __attribute__((ext_vector_type(8))) short bf16x8;
typedef __attribute__((ext_vector_type(4))) float f32x4;

// RNE f32->bf16 bit-trick (compiler-schedulable; do NOT use inline-asm cvt_pk — m240)
static __device__ __forceinline__ unsigned short f2bf(float f) {
  union { float f; unsigned int u; } v;
  v.f = f;
  unsigned int u = v.u;
  return (unsigned short)((u + 0x7FFFu + ((u >> 16) & 1u)) >> 16);
}

static __device__ __forceinline__ bf16x8 pack8(float4 a, float4 b) {
  bf16x8 r;
  r[0] = (short)f2bf(a.x); r[1] = (short)f2bf(a.y);
  r[2] = (short)f2bf(a.z); r[3] = (short)f2bf(a.w);
  r[4] = (short)f2bf(b.x); r[5] = (short)f2bf(b.y);
  r[6] = (short)f2bf(b.z); r[7] = (short)f2bf(b.w);
  return r;
}

// W1T[j][k] = bf16(W1[k][j]) (256x256); W2T[j][k] = bf16(W2[k][j]) (224x256, padded)
__global__ __launch_bounds__(256) void prep_kernel(
    const float* __restrict__ W1, const float* __restrict__ W2,
    unsigned short* __restrict__ w1t, unsigned short* __restrict__ w2t) {
  int j = blockIdx.x;
  int k = threadIdx.x;
  if (j < H) {
    w1t[j * H + k] = f2bf(W1[k * H + j]);
  } else {
    int jj = j - H;
    w2t[jj * H + k] = (jj < OUTD) ? f2bf(W2[k * OUTD + jj]) : (unsigned short)0;
  }
}

// raw barrier: drain own LDS ops, sync — global loads stay in flight
#define BAR()                                            \
  {                                                      \
    asm volatile("s_waitcnt lgkmcnt(0)" ::: "memory");   \
    __builtin_amdgcn_s_barrier();                        \
  }

__global__ __launch_bounds__(THREADS, 2) void fused_kernel(
    const float* __restrict__ pe, const float* __restrict__ b1g,
    const float* __restrict__ b2g, const unsigned short* __restrict__ w1t,
    const unsigned short* __restrict__ w2t, float* __restrict__ part) {
  // stage buffer eliminated (reg-staging); h gets its own buffer so GEMM1's
  // A-reads and the h-writes never alias -> GEMM1->h barrier removed.
  __shared__ __align__(16) unsigned short afrag[2 * BMT * H];  // 2 x 32 KB, fragment-linear bf16
  __shared__ __align__(16) unsigned short hbuf[BMT * H];       // 32 KB, fragment-linear bf16
  __shared__ __align__(16) float e_lds[BMT];

  const int tid = threadIdx.x;
  const int blk = blockIdx.x;
  const int w = tid >> 6;
  const int l = tid & 63;
  const int l15 = l & 15;
  const int hi = l >> 4;
  const size_t row0 = (size_t)blk * (BMT * TPB);   // 1024 rows/block, batch = blk>>2

  // ---- persistent B fragments (loaded once; steady-state VMEM = pe prefetch only) ----
  const int nct2 = (w < 6) ? 2 : 1;
  bf16x8 b1r[2][8], b2r[2][8];
  int jcol[2];
  float bc1[2], bj2[2];
  #pragma unroll
  for (int cc = 0; cc < 2; ++cc) {
    const int col1 = (2 * w + cc) * 16 + l15;
    const int ct2 = (w < 6) ? (2 * w + cc) : (6 + w);  // w6->12, w7->13
    const int col2 = ct2 * 16 + l15;
    jcol[cc] = col2;
    bc1[cc] = b1g[col1];
    bj2[cc] = (col2 < OUTD) ? b2g[col2] : 0.f;
    #pragma unroll
    for (int s = 0; s < 8; ++s) {
      const int k0 = s * 32 + hi * 8;
      b1r[cc][s] = *reinterpret_cast<const bf16x8*>(w1t + col1 * H + k0);
      b2r[cc][s] = *reinterpret_cast<const bf16x8*>(w2t + col2 * H + k0);
    }
  }
  const float b2c0 = b2g[0];

  // ---- reg-staged prefetch: tile T's pe rows -> ld[4][2] (32 VGPRs in flight) ----
  // unit idx = tid + j2*512: row = idx>>5, k8 = idx&31 -> lane's 32B at pe[row][k8*8..+7]
  // wave covers 2 contiguous rows (2 KB) per j2 -> fully coalesced
  float4 ld[4][2];
#define ISSUE(T)                                                             \
  {                                                                          \
    const float* g = pe + (row0 + (size_t)(T) * BMT) * H;                    \
    _Pragma("unroll") for (int j2 = 0; j2 < 4; ++j2) {                       \
      const int idx = tid + j2 * THREADS;                                    \
      const float* a = g + (idx >> 5) * H + (idx & 31) * 8;                  \
      ld[j2][0] = *(const float4*)a;                                         \
      ld[j2][1] = *(const float4*)(a + 4);                                   \
    }                                                                        \
  }

  // ---- convert: ld regs f32 -> afrag[buf] bf16, fragment-linear layout ----
  // element (row,k): f=row>>4, s=k8>>2; p = (ll*4 + hh + ss) & 63 (bank-uniform
  // write; matches GEMM read p = (l15*4 + hi + s) & 63 exactly — layout unchanged)
#define CVT(buf)                                                             \
  {                                                                          \
    unsigned short* dst = afrag + (buf) * (BMT * H);                         \
    _Pragma("unroll") for (int j2 = 0; j2 < 4; ++j2) {                       \
      const int idx = tid + j2 * THREADS;                                    \
      const int row = idx >> 5, k8 = idx & 31;                               \
      const int ff = row >> 4, ss = k8 >> 2, hh = k8 & 3, ll = row & 15;     \
      const int p = (ll * 4 + hh + ss) & 63;                                 \
      *(bf16x8*)&dst[(ff * 8 + ss) * 512 + p * 8] = pack8(ld[j2][0], ld[j2][1]); \
    }                                                                        \
  }

  // ---- prologue: stage tile 0, put tile 1 in flight ----
  ISSUE(0);
  __builtin_amdgcn_sched_barrier(0);
  CVT(0);
  BAR();
  ISSUE(1);

  float psum[2] = {0.f, 0.f};
  float dsum = 0.f;
  int cur = 0;

  for (int t = 0; t < TPB; ++t) {
    const unsigned short* A = afrag + cur * (BMT * H);

    // ---- GEMM1: 4 f-frags x 2 coltiles, k=256, reads afrag[cur] ----
    f32x4 acc[4][2];
    #pragma unroll
    for (int f = 0; f < 4; ++f) { acc[f][0] = (f32x4)0.f; acc[f][1] = (f32x4)0.f; }
    #pragma unroll
    for (int s = 0; s < 8; ++s) {
      const int p = (l15 * 4 + hi + s) & 63;
      bf16x8 af[4];
      #pragma unroll
      for (int f = 0; f < 4; ++f)
        af[f] = *(const bf16x8*)&A[(f * 8 + s) * 512 + p * 8];
      #pragma unroll
      for (int f = 0; f < 4; ++f) {
        acc[f][0] = __builtin_amdgcn_mfma_f32_16x16x32_bf16(af[f], b1r[0][s], acc[f][0], 0, 0, 0);
        acc[f][1] = __builtin_amdgcn_mfma_f32_16x16x32_bf16(af[f], b1r[1][s], acc[f][1], 0, 0, 0);
      }
    }

    // ---- h = leaky(acc + b1) -> hbuf (own-wave data; no barrier needed before) ----
    // prior tile's GEMM2 hbuf-reads all completed before last iteration's BAR2
    #pragma unroll
    for (int cc = 0; cc < 2; ++cc) {
      const int col_c0 = (2 * w + cc) * 16 + l15;     // GEMM1 output col
      const int s2 = col_c0 >> 5;
      const int hb = (col_c0 >> 3) & 3;
      const int j2 = col_c0 & 7;
      #pragma unroll
      for (int f = 0; f < 4; ++f) {
        #pragma unroll
        for (int r = 0; r < 4; ++r) {
          const int rl = hi * 4 + r;                  // row_c & 15
          float hv = acc[f][cc][r] + bc1[cc];
          hv = fmaxf(hv, 0.02f * hv);                 // leaky relu
          const int p2 = (rl * 4 + hb + s2) & 63;
          hbuf[(f * 8 + s2) * 512 + p2 * 8 + j2] = f2bf(hv);
        }
      }
    }
    BAR();  // BAR1: h visible to all waves

    // ---- GEMM2: ae = h @ W2, reads hbuf ----
    #pragma unroll
    for (int f = 0; f < 4; ++f) { acc[f][0] = (f32x4)0.f; acc[f][1] = (f32x4)0.f; }
    #pragma unroll
    for (int s = 0; s < 8; ++s) {
      const int p = (l15 * 4 + hi + s) & 63;
      bf16x8 af[4];
      #pragma unroll
      for (int f = 0; f < 4; ++f)
        af[f] = *(const bf16x8*)&hbuf[(f * 8 + s) * 512 + p * 8];
      #pragma unroll
      for (int f = 0; f < 4; ++f) {
        acc[f][0] = __builtin_amdgcn_mfma_f32_16x16x32_bf16(af[f], b2r[0][s], acc[f][0], 0, 0, 0);
      }
      if (nct2 == 2) {
        #pragma unroll
        for (int f = 0; f < 4; ++f) {
          acc[f][1] = __builtin_amdgcn_mfma_f32_16x16x32_bf16(af[f], b2r[1][s], acc[f][1], 0, 0, 0);
        }
      }
    }

    // ---- e = exp(logit): col 0 lives in wave 0, lanes l15==0 ----
    if (w == 0 && l15 == 0) {
      #pragma unroll
      for (int f = 0; f < 4; ++f) {
        #pragma unroll
        for (int r = 0; r < 4; ++r) {
          e_lds[f * 16 + hi * 4 + r] = __expf(acc[f][0][r] + b2c0);
        }
      }
    }

    // ---- convert next tile into afrag[cur^1] (its own sched region, NOT in
    // the MFMA loop); afrag[cur^1]'s last readers finished at BAR1 of tile t-1.
    if (t + 1 < TPB) {
      __builtin_amdgcn_sched_barrier(0);
      CVT(cur ^ 1);
      __builtin_amdgcn_sched_barrier(0);
    }
    BAR();  // BAR2: e_lds + converted afrag visible; all hbuf reads done

    // ---- accumulate softmax-weighted partials in registers ----
    #pragma unroll
    for (int f = 0; f < 4; ++f) {
      const f32x4 ev = *(const f32x4*)&e_lds[f * 16 + hi * 4];
      #pragma unroll
      for (int r = 0; r < 4; ++r) {
        psum[0] += ev[r] * (acc[f][0][r] + bj2[0]);
        if (nct2 == 2) psum[1] += ev[r] * (acc[f][1][r] + bj2[1]);
      }
    }
    if (w == 1) dsum += e_lds[l];

    // ---- prefetch tile t+2 (ld regs freed by CVT above; full tile of flight) ----
    if (t + 2 < TPB) ISSUE(t + 2);

    cur ^= 1;
  }

  // ---- store per-block partials (no atomics) ----
  #pragma unroll
  for (int cc = 0; cc < 2; ++cc) {
    psum[cc] += __shfl_xor(psum[cc], 16);
    psum[cc] += __shfl_xor(psum[cc], 32);
  }
  if (hi == 0) {
    for (int cc = 0; cc < nct2; ++cc) {
      int j = jcol[cc];
      if (j >= 1 && j < OUTD) part[blk * PCOLS + (j - 1)] = psum[cc];
    }
  }
  if (w == 1) {
    #pragma unroll
    for (int m = 1; m < 64; m <<= 1) dsum += __shfl_xor(dsum, m);
    if (l == 0) part[blk * PCOLS + 217] = dsum;
  }
#undef ISSUE
#undef CVT
}

__global__ __launch_bounds__(256) void finalize_kernel(
    const float* __restrict__ part, float* __restrict__ out) {
  int b = blockIdx.x;
  int t = threadIdx.x;
  if (t < 217) {
    float s = 0.f, d = 0.f;
    #pragma unroll
    for (int i = 0; i < NBLK / NBATCH; ++i) {   // 4 blocks per batch
      const float* p = part + (size_t)(b * (NBLK / NBATCH) + i) * PCOLS;
      s += p[t];
      d += p[217];
    }
    float v = s / d;
    if (t < 216) out[b * 216 + t] = v;        // xr: (64, 72, 3) flat
    else out[NBATCH * 216 + b] = v;           // xo: (64,)
  }
}

extern "C" void kernel_launch(void* const* d_in, const int* in_sizes, int n_in,
                              void* d_out, int out_size, void* d_ws, size_t ws_size,
                              hipStream_t stream) {
  (void)in_sizes; (void)n_in; (void)out_size; (void)ws_size;
  const float* pe = (const float*)d_in[0];
  const float* W1 = (const float*)d_in[1];
  const float* b1 = (const float*)d_in[2];
  const float* W2 = (const float*)d_in[3];
  const float* b2 = (const float*)d_in[4];

  unsigned short* w1t = (unsigned short*)d_ws;          // 131072 B
  unsigned short* w2t = w1t + H * H;                    // 114688 B
  float* part = (float*)((char*)d_ws + (H * H + OUTP * H) * 2);  // 256*218*4 B

  prep_kernel<<<H + OUTP, 256, 0, stream>>>(W1, W2, w1t, w2t);
  fused_kernel<<<NBLK, THREADS, 0, stream>>>(pe, b1, b2, w1t, w2t, part);
  finalize_kernel<<<NBATCH, 256, 0, stream>>>(part, (float*)d_out);
}